// Round 1
// 1090.191 us; speedup vs baseline: 1.0484x; 1.0484x over previous
//
#include <hip/hip_runtime.h>
#include <stdint.h>

#define HDIM 256
#define SEQ  784
#define NB   256
#define NCLS 10
#define NTHR 512
#define RQ   48              // weight quads per thread held in VGPRs (192 VGPRs)
#define LQ   16              // weight quads per thread held in LDS (128 KB)
#define NQ   64              // total quads per thread (= 64 k-pairs x 4 gates)

typedef _Float16 half2_t __attribute__((ext_vector_type(2)));

__device__ __forceinline__ half2_t u2h(uint32_t u) {
    union { uint32_t u; half2_t h; } v; v.u = u; return v.h;
}
__device__ __forceinline__ uint32_t pkf16(float a, float b) {
    union { half2_t h; uint32_t u; } v;
    v.h.x = (_Float16)a; v.h.y = (_Float16)b; return v.u;
}

#if __has_builtin(__builtin_amdgcn_fdot2)
__device__ __forceinline__ float dot2(uint32_t h, uint32_t w, float acc) {
    return __builtin_amdgcn_fdot2(u2h(h), u2h(w), acc, false);
}
#else
__device__ __forceinline__ float dot2(uint32_t h, uint32_t w, float acc) {
    half2_t hv = u2h(h), wv = u2h(w);
    acc = fmaf((float)hv.x, (float)wv.x, acc);
    return fmaf((float)hv.y, (float)wv.y, acc);
}
#endif

#if __has_builtin(__builtin_amdgcn_rcpf)
__device__ __forceinline__ float fast_rcp(float x) { return __builtin_amdgcn_rcpf(x); }
#else
__device__ __forceinline__ float fast_rcp(float x) { return 1.f / x; }
#endif

// sigma(x) = 1/(1+e^-x); tanh(x) = 2*sigma(2x) - 1.  v_exp/v_rcp ~1ulp each.
__device__ __forceinline__ float sigmoid_f(float x) {
    return fast_rcp(1.f + __expf(-x));
}
__device__ __forceinline__ float tanh_f(float x) {
    return fmaf(2.f, fast_rcp(1.f + __expf(-2.f * x)), -1.f);
}

// WP[q*NTHR + t], t=(r<<1)|kh: quad = {G,I,F,O} f16-pairs for row r, k = kh*128 + 2q
__global__ __launch_bounds__(NTHR) void pack_w16(
    const float* __restrict__ Wg, const float* __restrict__ Wi,
    const float* __restrict__ Wf, const float* __restrict__ Wo,
    uint4* __restrict__ WP)
{
    const int q = blockIdx.x;          // 0..63
    const int t = threadIdx.x;         // 0..511
    const int r = t >> 1, kh = t & 1;
    const int k = kh * 128 + 2 * q;
    const int s = r * HDIM + k;
    uint4 v;
    v.x = pkf16(Wg[s], Wg[s + 1]);
    v.y = pkf16(Wi[s], Wi[s + 1]);
    v.z = pkf16(Wf[s], Wf[s + 1]);
    v.w = pkf16(Wo[s], Wo[s + 1]);
    WP[q * NTHR + t] = v;
}

__global__ void __launch_bounds__(NTHR)
__attribute__((amdgpu_waves_per_eu(2, 2)))   // exactly 2 waves/EU -> 256 VGPR budget
lstm_f16(
    const float* __restrict__ x,
    const float* __restrict__ Wgx, const float* __restrict__ bg_,
    const float* __restrict__ Wix, const float* __restrict__ bi_,
    const float* __restrict__ Wfx, const float* __restrict__ bf_,
    const float* __restrict__ Wox, const float* __restrict__ bo_,
    const float* __restrict__ Wph, const float* __restrict__ bp_,
    const uint4* __restrict__ WP,
    float* __restrict__ out)
{
    // h buffer: kh=0 half at dwords [0..63], kh=1 half at dwords [68..131].
    // The +4-dword pad shifts the kh=1 addresses to a disjoint bank group, so the
    // per-wave 2-address broadcast read (kh=0 lanes @ A, kh=1 lanes @ A+272B) is
    // conflict-free (was: +256B = same banks = 4 conflict cycles per b128 read).
    __shared__ uint4 lws[LQ * NTHR];                       // 131,072 B
    __shared__ float xs[SEQ + 1];                          //   3,140 B (pad for x-precompute)
    __shared__ __align__(16) uint32_t hs[2][136];          //   1,088 B (h as f16 pairs, dbuf, padded)
    __shared__ float hfin[HDIM];                           //   1,024 B

    const int t = threadIdx.x;
    const int b = blockIdx.x;
    const int r = t >> 1;
    const int kh = t & 1;

    for (int i = t; i < SEQ; i += NTHR) xs[i] = x[b * SEQ + i];
    if (t == 0) xs[SEQ] = 0.f;
    if (t < 136) hs[0][t] = 0u;

    // LDS-resident quads are q = 0..LQ-1 (consumed FIRST each ts so their ds_read
    // temps are short-lived); register quads are q = LQ..NQ-1 (long-lived, should
    // stay in arch VGPRs: 192 regs + ~50 overhead < 256 budget -> no AGPR copies).
    #pragma unroll
    for (int c = 0; c < LQ; ++c) lws[c * NTHR + t] = WP[c * NTHR + t];

    uint4 wq[RQ];
    #pragma unroll
    for (int i = 0; i < RQ; ++i) wq[i] = WP[(LQ + i) * NTHR + t];

    // x-term + bias contributed by the kh==0 thread ONLY (the shfl_xor reduce
    // sums both k-half partials). Fold the gate into the coefficients.
    const float xsc = (kh == 0) ? 1.f : 0.f;
    const float wgxe = xsc * Wgx[r], wixe = xsc * Wix[r];
    const float wfxe = xsc * Wfx[r], woxe = xsc * Wox[r];
    const float bge = xsc * bg_[b], bie = xsc * bi_[b];
    const float bfe = xsc * bf_[b], boe = xsc * bo_[b];

    float cst = 0.f, hcur = 0.f;

    __syncthreads();

    float ag = fmaf(wgxe, xs[0], bge);
    float ai = fmaf(wixe, xs[0], bie);
    float af = fmaf(wfxe, xs[0], bfe);
    float ao = fmaf(woxe, xs[0], boe);

    #pragma unroll 1
    for (int ts = 0; ts < SEQ; ++ts) {
        const int cur = ts & 1;
        const uint4* hsv = (const uint4*)(&hs[cur][0] + kh * 68);

        // --- LDS-resident weight quads first (chunks 0..LQ/4-1) ---
        #pragma unroll
        for (int ch = 0; ch < LQ / 4; ++ch) {
            const uint4 hh = hsv[ch];
            const uint32_t hx[4] = { hh.x, hh.y, hh.z, hh.w };
            #pragma unroll
            for (int e = 0; e < 4; ++e) {
                const uint4 w = lws[(ch * 4 + e) * NTHR + t];
                ag = dot2(hx[e], w.x, ag);
                ai = dot2(hx[e], w.y, ai);
                af = dot2(hx[e], w.z, af);
                ao = dot2(hx[e], w.w, ao);
            }
        }
        // --- register-resident weight quads (chunks LQ/4..15) ---
        #pragma unroll
        for (int ch = LQ / 4; ch < NQ / 4; ++ch) {
            const uint4 hh = hsv[ch];
            const uint32_t hx[4] = { hh.x, hh.y, hh.z, hh.w };
            #pragma unroll
            for (int e = 0; e < 4; ++e) {
                const uint4 w = wq[ch * 4 + e - LQ];
                ag = dot2(hx[e], w.x, ag);
                ai = dot2(hx[e], w.y, ai);
                af = dot2(hx[e], w.z, af);
                ao = dot2(hx[e], w.w, ao);
            }
        }

        ag += __shfl_xor(ag, 1);
        ai += __shfl_xor(ai, 1);
        af += __shfl_xor(af, 1);
        ao += __shfl_xor(ao, 1);

        const float g  = tanh_f(ag);
        const float iv = sigmoid_f(ai);
        const float fv = sigmoid_f(af);
        const float ov = sigmoid_f(ao);
        cst  = fmaf(g, iv, cst * fv);
        hcur = tanh_f(cst) * ov;

        // padded write: r<128 -> half index r; r>=128 -> r+8 (skip the 4-dword pad)
        if (kh == 0) ((_Float16*)&hs[cur ^ 1][0])[r + ((r >> 7) << 3)] = (_Float16)hcur;

        // precompute next ts's x-term before the barrier (off the critical path;
        // xs is constant, so reading it pre-barrier is safe)
        const float xn = xs[ts + 1];
        ag = fmaf(wgxe, xn, bge);
        ai = fmaf(wixe, xn, bie);
        af = fmaf(wfxe, xn, bfe);
        ao = fmaf(woxe, xn, boe);

        __syncthreads();   // writes to hs[cur^1] visible; all reads of hs[cur] were pre-barrier
    }

    if (kh == 0) hfin[r] = hcur;
    __syncthreads();

    if (t < NCLS) {
        float acc = bp_[b];
        #pragma unroll 4
        for (int k = 0; k < HDIM; ++k) acc = fmaf(Wph[t * HDIM + k], hfin[k], acc);
        out[b * NCLS + t] = acc;
    }
}

// Fallback (no workspace): fp32 weights streamed from L2. Correctness insurance only.
__global__ __launch_bounds__(HDIM) void lstm_fb(
    const float* __restrict__ x,
    const float* __restrict__ Wgx, const float* __restrict__ Wgh, const float* __restrict__ bg_,
    const float* __restrict__ Wix, const float* __restrict__ Wih, const float* __restrict__ bi_,
    const float* __restrict__ Wfx, const float* __restrict__ Wfh, const float* __restrict__ bf_,
    const float* __restrict__ Wox, const float* __restrict__ Woh, const float* __restrict__ bo_,
    const float* __restrict__ Wph, const float* __restrict__ bp_,
    float* __restrict__ out)
{
    __shared__ float xs[SEQ];
    __shared__ float hsv[HDIM];
    const int r = threadIdx.x, b = blockIdx.x;
    for (int i = r; i < SEQ; i += HDIM) xs[i] = x[b * SEQ + i];
    hsv[r] = 0.f;
    float c = 0.f;
    const float wgx = Wgx[r], wix = Wix[r], wfx = Wfx[r], wox = Wox[r];
    const float bg = bg_[b], bi = bi_[b], bfv = bf_[b], bo = bo_[b];
    __syncthreads();
    for (int ts = 0; ts < SEQ; ++ts) {
        const float xt = xs[ts];
        float ag = fmaf(wgx, xt, bg);
        float ai = fmaf(wix, xt, bi);
        float af = fmaf(wfx, xt, bfv);
        float ao = fmaf(wox, xt, bo);
        #pragma unroll 4
        for (int k = 0; k < HDIM; ++k) {
            const float hv = hsv[k];
            ag = fmaf(Wgh[r * HDIM + k], hv, ag);
            ai = fmaf(Wih[r * HDIM + k], hv, ai);
            af = fmaf(Wfh[r * HDIM + k], hv, af);
            ao = fmaf(Woh[r * HDIM + k], hv, ao);
        }
        const float g  = tanhf(ag);
        const float iv = 1.f / (1.f + expf(-ai));
        const float fv = 1.f / (1.f + expf(-af));
        const float ov = 1.f / (1.f + expf(-ao));
        c = fmaf(g, iv, c * fv);
        const float hn = tanhf(c) * ov;
        __syncthreads();
        hsv[r] = hn;
        __syncthreads();
    }
    if (r < NCLS) {
        float acc = bp_[b];
        for (int k = 0; k < HDIM; ++k) acc = fmaf(Wph[r * HDIM + k], hsv[k], acc);
        out[b * NCLS + r] = acc;
    }
}

extern "C" void kernel_launch(void* const* d_in, const int* in_sizes, int n_in,
                              void* d_out, int out_size, void* d_ws, size_t ws_size,
                              hipStream_t stream) {
    const float* x   = (const float*)d_in[0];
    const float* Wgx = (const float*)d_in[1];
    const float* Wgh = (const float*)d_in[2];
    const float* bg  = (const float*)d_in[3];
    const float* Wix = (const float*)d_in[4];
    const float* Wih = (const float*)d_in[5];
    const float* bi  = (const float*)d_in[6];
    const float* Wfx = (const float*)d_in[7];
    const float* Wfh = (const float*)d_in[8];
    const float* bf  = (const float*)d_in[9];
    const float* Wox = (const float*)d_in[10];
    const float* Woh = (const float*)d_in[11];
    const float* bo  = (const float*)d_in[12];
    const float* Wph = (const float*)d_in[13];
    const float* bp  = (const float*)d_in[14];
    float* out = (float*)d_out;

    const size_t need = (size_t)NQ * NTHR * sizeof(uint4);   // 512 KB
    if (ws_size >= need) {
        uint4* WP = (uint4*)d_ws;
        pack_w16<<<dim3(NQ), dim3(NTHR), 0, stream>>>(Wgh, Wih, Wfh, Woh, WP);
        lstm_f16<<<dim3(NB), dim3(NTHR), 0, stream>>>(
            x, Wgx, bg, Wix, bi, Wfx, bf, Wox, bo, Wph, bp, (const uint4*)WP, out);
    } else {
        lstm_fb<<<dim3(NB), dim3(HDIM), 0, stream>>>(
            x, Wgx, Wgh, bg, Wix, Wih, bi, Wfx, Wfh, bf, Wox, Woh, bo, Wph, bp, out);
    }
}